// Round 3
// baseline (1867.311 us; speedup 1.0000x reference)
//
#include <hip/hip_runtime.h>

// UnMaxPoolWithArgmax via hierarchical 64x64 counting sort (no global atomics,
// line-complete coalesced writes everywhere).
// in:   (B=8, H=512, W=256, C=64) f32 ; mask: same shape, int32 in [0, 2^24)
// out:  (8, 1024, 256, 64) f32, scatter-add semantics.
// target = (b<<24) | (mask & ~63) | c  (27 bits)
// coarse = target>>21 (64), fine-global = target>>15 (4096), slot = target&32767

typedef unsigned int u32;
typedef unsigned short u16;

constexpr long long N_IN = 1LL << 26;      // 67,108,864 elements
constexpr int RSH    = 15;                 // final region = 2^15 slots (128 KiB)
constexpr int RSLOTS = 1 << RSH;

// ---------- new path geometry ----------
constexpr int SBS   = 4096;                // records per sort batch / sub-batch
constexpr int NSB   = (int)(N_IN / SBS);   // 16384 sub-batches
constexpr int A_T   = 512;
constexpr int A_BATCHES = 8;               // sub-batches per passA block
constexpr int NTILE = NSB / A_BATCHES;     // 2048 passA blocks
constexpr int NC    = 64;                  // coarse buckets
constexpr int NFG   = 4096;                // global fine buckets
constexpr int NFL   = 64;                  // fine buckets per coarse
constexpr int NR    = 32;                  // passB ranges per coarse bucket
constexpr int TILES_PER_R = NTILE / NR;    // 64
constexpr int SB_PER_R    = NSB / NR;      // 512 sub-batch chunks per passB block

// ---------- new path workspace ----------
constexpr size_t OFF2_IDXA = 0;                                    // u32[2^26]
constexpr size_t OFF2_VALA = OFF2_IDXA + (1ULL << 28);             // f32[2^26]
constexpr size_t OFF2_IDXB = OFF2_VALA + (1ULL << 28);             // u16[2^26]
constexpr size_t OFF2_VALB = OFF2_IDXB + (1ULL << 27);             // f32[2^26]
constexpr size_t OFF2_DIRA = OFF2_VALB + (1ULL << 28);             // u32[NSB*NC]
constexpr size_t OFF2_DIRF = OFF2_DIRA + (size_t)NSB * NC * 4;     // u32[NTILE*NFG]
constexpr size_t OFF2_RS   = OFF2_DIRF + (size_t)NTILE * NFG * 4;  // u32[NR*NFG]
constexpr size_t OFF2_BB   = OFF2_RS + (size_t)NR * NFG * 4;       // u32[NR*NFG]
constexpr size_t OFF2_TOT  = OFF2_BB + (size_t)NR * NFG * 4;       // u32[NFG]
constexpr size_t OFF2_FB   = OFF2_TOT + (size_t)NFG * 4;           // u32[NFG+1]
constexpr size_t WS2_NEED  = OFF2_FB + (size_t)(NFG + 1) * 4;      // ~933 MiB

// ============================ passA ============================
// Sort each 4096-elem sub-batch by coarse bucket in LDS; flush coalesced.
// Also per-tile fine histogram -> dirF.
__global__ __launch_bounds__(A_T) void passA(const float* __restrict__ in,
                                             const int* __restrict__ mask,
                                             u32* __restrict__ idxA,
                                             float* __restrict__ valA,
                                             u32* __restrict__ dirA,
                                             u32* __restrict__ dirF)
{
    __shared__ u32 histC[NC];       // per-batch coarse hist -> cursors
    __shared__ u32 histF[NFG];      // per-tile fine hist (16 KB)
    __shared__ u32 sIdx[SBS];       // 16 KB
    __shared__ float sVal[SBS];     // 16 KB
    const int tid = threadIdx.x;
    const int t   = blockIdx.x;

    for (int i = tid; i < NFG; i += A_T) histF[i] = 0;

    for (int batch = 0; batch < A_BATCHES; ++batch) {
        const int sb = t * A_BATCHES + batch;
        const int e0 = sb * SBS + tid * 8;     // < 2^26
        const int4*   m4 = (const int4*)mask + (e0 >> 2);
        const float4* v4 = (const float4*)in + (e0 >> 2);
        int4 ma = m4[0], mb = m4[1];
        float4 va = v4[0], vb = v4[1];
        const u32 bb = ((u32)(e0 >> 23)) << 24;
        const u32 c0 = (u32)(e0 & 63);

        u32 tg[8]; float vv[8];
        tg[0] = bb + (((u32)ma.x) & ~63u) + c0 + 0; vv[0] = va.x;
        tg[1] = bb + (((u32)ma.y) & ~63u) + c0 + 1; vv[1] = va.y;
        tg[2] = bb + (((u32)ma.z) & ~63u) + c0 + 2; vv[2] = va.z;
        tg[3] = bb + (((u32)ma.w) & ~63u) + c0 + 3; vv[3] = va.w;
        tg[4] = bb + (((u32)mb.x) & ~63u) + c0 + 4; vv[4] = vb.x;
        tg[5] = bb + (((u32)mb.y) & ~63u) + c0 + 5; vv[5] = vb.y;
        tg[6] = bb + (((u32)mb.z) & ~63u) + c0 + 6; vv[6] = vb.z;
        tg[7] = bb + (((u32)mb.w) & ~63u) + c0 + 7; vv[7] = vb.w;

        if (tid < NC) histC[tid] = 0;
        __syncthreads();
#pragma unroll
        for (int j = 0; j < 8; ++j) {
            atomicAdd(&histC[tg[j] >> 21], 1u);
            atomicAdd(&histF[tg[j] >> 15], 1u);
        }
        __syncthreads();
        if (tid < 64) {
            u32 x = histC[tid];
            u32 s = x;
#pragma unroll
            for (int d = 1; d < 64; d <<= 1) {
                u32 n = __shfl_up(s, (unsigned)d, 64);
                if (tid >= d) s += n;
            }
            u32 ex = s - x;                       // exclusive scan
            dirA[(size_t)sb * NC + tid] = (u32)(sb * SBS) + ex;
            histC[tid] = ex;                      // cursor
        }
        __syncthreads();
#pragma unroll
        for (int j = 0; j < 8; ++j) {
            u32 p = atomicAdd(&histC[tg[j] >> 21], 1u);
            sIdx[p] = tg[j] & 0x1FFFFFu;          // rel21
            sVal[p] = vv[j];
        }
        __syncthreads();
#pragma unroll
        for (int k = 0; k < 8; ++k) {
            int i = tid + k * A_T;
            idxA[(size_t)sb * SBS + i] = sIdx[i];
            valA[(size_t)sb * SBS + i] = sVal[i];
        }
        __syncthreads();
    }
    for (int i = tid; i < NFG; i += A_T) dirF[(size_t)t * NFG + i] = histF[i];
}

// ============================ mid1 ============================
// rangeSum[r][f] = sum of dirF over tiles in range r; totalF[f] = sum over all.
__global__ __launch_bounds__(256) void mid1(const u32* __restrict__ dirF,
                                            u32* __restrict__ rangeSum,
                                            u32* __restrict__ totalF)
{
    const int f = blockIdx.x * 256 + threadIdx.x;    // 16 blocks -> 4096
    u32 tot = 0;
    for (int r = 0; r < NR; ++r) {
        u32 s = 0;
        for (int k = 0; k < TILES_PER_R; ++k) {
            int t = r * TILES_PER_R + k;
            s += dirF[(size_t)t * NFG + f];
        }
        rangeSum[(size_t)r * NFG + f] = s;
        tot += s;
    }
    totalF[f] = tot;
}

// ============================ mid2 ============================
// fineBase = exclusive scan of totalF; baseB[r][f] = fineBase[f] + prefix of rangeSum.
__global__ __launch_bounds__(1024) void mid2(const u32* __restrict__ totalF,
                                             const u32* __restrict__ rangeSum,
                                             u32* __restrict__ fineBase,
                                             u32* __restrict__ baseB)
{
    __shared__ u32 sT[NFG];
    __shared__ u32 wS[16];
    const int tid = threadIdx.x;
    for (int i = tid; i < NFG; i += 1024) sT[i] = totalF[i];
    __syncthreads();
    u32 a0 = sT[tid * 4 + 0], a1 = sT[tid * 4 + 1];
    u32 a2 = sT[tid * 4 + 2], a3 = sT[tid * 4 + 3];
    u32 sum = a0 + a1 + a2 + a3;
    u32 s = sum;
    const int lane = tid & 63;
#pragma unroll
    for (int d = 1; d < 64; d <<= 1) {
        u32 n = __shfl_up(s, (unsigned)d, 64);
        if (lane >= d) s += n;
    }
    if (lane == 63) wS[tid >> 6] = s;
    u32 exw = s - sum;
    __syncthreads();
    if (tid == 0) {
        u32 run = 0;
        for (int w = 0; w < 16; ++w) { u32 x = wS[w]; wS[w] = run; run += x; }
    }
    __syncthreads();
    u32 base = wS[tid >> 6] + exw;
    u32 b0 = base, b1 = base + a0, b2 = b1 + a1, b3 = b2 + a2;
    fineBase[tid * 4 + 0] = b0;
    fineBase[tid * 4 + 1] = b1;
    fineBase[tid * 4 + 2] = b2;
    fineBase[tid * 4 + 3] = b3;
    if (tid == 0) fineBase[NFG] = (u32)N_IN;
    u32 c0_ = b0, c1_ = b1, c2_ = b2, c3_ = b3;
    for (int r = 0; r < NR; ++r) {
        baseB[(size_t)r * NFG + tid * 4 + 0] = c0_; c0_ += rangeSum[(size_t)r * NFG + tid * 4 + 0];
        baseB[(size_t)r * NFG + tid * 4 + 1] = c1_; c1_ += rangeSum[(size_t)r * NFG + tid * 4 + 1];
        baseB[(size_t)r * NFG + tid * 4 + 2] = c2_; c2_ += rangeSum[(size_t)r * NFG + tid * 4 + 2];
        baseB[(size_t)r * NFG + tid * 4 + 3] = c3_; c3_ += rangeSum[(size_t)r * NFG + tid * 4 + 3];
    }
}

// ============================ passB ============================
// Block = (coarse c, range r). Gather this coarse bucket's records from 512
// sub-batch chunks, sort each 4096-record batch by fine bucket in LDS, flush
// to exact contiguous fine-major regions.
__global__ __launch_bounds__(512) void passB(const u32* __restrict__ idxA,
                                             const float* __restrict__ valA,
                                             const u32* __restrict__ dirA,
                                             const u32* __restrict__ baseB,
                                             u16* __restrict__ idxB,
                                             float* __restrict__ valB)
{
    __shared__ u32 chunkSrc[SB_PER_R];
    __shared__ u32 chunkDst[SB_PER_R + 1];
    __shared__ u32 histB[NFL];
    __shared__ u32 scanB[NFL];
    __shared__ u32 batchCnt[NFL];
    __shared__ u32 curG[NFL];
    __shared__ u16 sU[SBS];          // 8 KB
    __shared__ float sV[SBS];        // 16 KB
    __shared__ u32 sD[SBS];          // 16 KB
    __shared__ u32 wS[8];

    const int tid = threadIdx.x;
    const int c = blockIdx.x >> 5;       // / NR
    const int r = blockIdx.x & (NR - 1);

    // build chunk table (one chunk per thread)
    {
        const int sb = r * SB_PER_R + tid;
        u32 st = dirA[(size_t)sb * NC + c];
        u32 en = (c < NC - 1) ? dirA[(size_t)sb * NC + c + 1] : (u32)((sb + 1) * SBS);
        u32 len = en - st;
        chunkSrc[tid] = st;
        u32 s = len;
        const int lane = tid & 63;
#pragma unroll
        for (int d = 1; d < 64; d <<= 1) {
            u32 n = __shfl_up(s, (unsigned)d, 64);
            if (lane >= d) s += n;
        }
        if (lane == 63) wS[tid >> 6] = s;
        u32 exw = s - len;
        __syncthreads();
        if (tid == 0) {
            u32 run = 0;
            for (int w = 0; w < 8; ++w) { u32 x = wS[w]; wS[w] = run; run += x; }
        }
        __syncthreads();
        u32 dst = wS[tid >> 6] + exw;
        chunkDst[tid] = dst;
        if (tid == SB_PER_R - 1) chunkDst[SB_PER_R] = dst + len;
    }
    if (tid < NFL) curG[tid] = baseB[(size_t)r * NFG + c * NFL + tid];
    __syncthreads();

    const u32 total = chunkDst[SB_PER_R];
    const int nbatch = (int)((total + SBS - 1) / SBS);

    for (int bt = 0; bt < nbatch; ++bt) {
        const u32 q0 = (u32)bt * SBS;
        const u32 qn = (total - q0 < (u32)SBS) ? (total - q0) : (u32)SBS;
        if (tid < NFL) histB[tid] = 0;
        __syncthreads();

        u32 rel[8]; float vv[8]; u32 fl[8];
#pragma unroll
        for (int k = 0; k < 8; ++k) {
            fl[k] = 0xFFFFFFFFu;
            u32 off = (u32)tid + (u32)(k * 512);
            if (off < qn) {
                u32 q = q0 + off;
                int lo = 0, hi = SB_PER_R;
                while (hi - lo > 1) {
                    int md = (lo + hi) >> 1;
                    if (chunkDst[md] <= q) lo = md; else hi = md;
                }
                u32 src = chunkSrc[lo] + (q - chunkDst[lo]);
                u32 rv = idxA[src];
                vv[k] = valA[src];
                rel[k] = rv & 0x7FFFu;
                fl[k] = rv >> 15;                 // 0..63
                atomicAdd(&histB[fl[k]], 1u);
            }
        }
        __syncthreads();
        if (tid < 64) {
            u32 x = histB[tid];
            batchCnt[tid] = x;
            u32 s = x;
#pragma unroll
            for (int d = 1; d < 64; d <<= 1) {
                u32 n = __shfl_up(s, (unsigned)d, 64);
                if (tid >= d) s += n;
            }
            u32 ex = s - x;
            scanB[tid] = ex;
            histB[tid] = ex;                      // cursor
        }
        __syncthreads();
#pragma unroll
        for (int k = 0; k < 8; ++k) {
            if (fl[k] != 0xFFFFFFFFu) {
                u32 p = atomicAdd(&histB[fl[k]], 1u);
                sU[p] = (u16)rel[k];
                sV[p] = vv[k];
                sD[p] = curG[fl[k]] + (p - scanB[fl[k]]);
            }
        }
        __syncthreads();
        for (u32 i = tid; i < qn; i += 512) {
            u32 g = sD[i];
            idxB[g] = sU[i];
            valB[g] = sV[i];
        }
        if (tid < NFL) curG[tid] += batchCnt[tid];
        __syncthreads();
    }
}

// ============================ passC ============================
// One block per fine bucket: contiguous record region -> LDS accumulate -> store.
__global__ __launch_bounds__(1024) void passC(const u16* __restrict__ idxB,
                                              const float* __restrict__ valB,
                                              const u32* __restrict__ fineBase,
                                              float* __restrict__ out)
{
    __shared__ float acc[RSLOTS];    // 128 KB
    const int tid = threadIdx.x;
    const int fb = blockIdx.x;
    for (int i = tid; i < RSLOTS; i += 1024) acc[i] = 0.f;
    const u32 st = fineBase[fb], en = fineBase[fb + 1];
    __syncthreads();
    for (u32 k = st + (u32)tid; k < en; k += 1024) {
        atomicAdd(&acc[idxB[k]], valB[k]);
    }
    __syncthreads();
    float4* o4 = (float4*)out + ((size_t)fb << (RSH - 2));
    const float4* a4 = (const float4*)acc;
    for (int i = tid; i < RSLOTS / 4; i += 1024) o4[i] = a4[i];
}

// ===================== fallback: round-2 two-phase binning =====================
constexpr int  FB_NBCK = 4096;
constexpr int  FB_TILE = 1 << 17;
constexpr int  FB_NTILES = (int)(N_IN / FB_TILE);    // 512
constexpr int  P1T = 512;
constexpr int  P2T = 1024;
constexpr size_t OFF_VAL = 0;
constexpr size_t OFF_IDX = (size_t)N_IN * 4;
constexpr size_t OFF_DIR = OFF_IDX + (size_t)N_IN * 2;
constexpr size_t WS_NEED = OFF_DIR + (size_t)FB_NTILES * FB_NBCK * 4;

__global__ __launch_bounds__(P1T) void p1_bin(const float* __restrict__ in,
                                              const int* __restrict__ mask,
                                              float* __restrict__ wval,
                                              u16* __restrict__ widx,
                                              u32* __restrict__ dir)
{
    __shared__ u32 hist[FB_NBCK];
    __shared__ u32 wsum[P1T / 64];
    const int tid = threadIdx.x;
    const int lane = tid & 63;
    const int wid = tid >> 6;
    const int t = blockIdx.x;
    const int tilebase = t * FB_TILE;
    const int g4base = tilebase >> 2;

    for (int i = tid; i < FB_NBCK; i += P1T) hist[i] = 0;
    __syncthreads();

    const int4* m4 = (const int4*)mask;
    const float4* v4 = (const float4*)in;

    for (int it = 0; it < FB_TILE / 4 / P1T; ++it) {
        int gi = tid + it * P1T;
        int4 m = m4[g4base + gi];
        int e0 = tilebase + gi * 4;
        u32 ob = ((u32)(e0 >> 23)) << 24;
        atomicAdd(&hist[(ob + (u32)(m.x & ~63)) >> RSH], 1u);
        atomicAdd(&hist[(ob + (u32)(m.y & ~63)) >> RSH], 1u);
        atomicAdd(&hist[(ob + (u32)(m.z & ~63)) >> RSH], 1u);
        atomicAdd(&hist[(ob + (u32)(m.w & ~63)) >> RSH], 1u);
    }
    __syncthreads();

    u32 cch[8];
    u32 run = 0;
    const int b0 = tid * (FB_NBCK / P1T);
#pragma unroll
    for (int j = 0; j < 8; ++j) { u32 x = hist[b0 + j]; cch[j] = run; run += x; }
    u32 x = run;
#pragma unroll
    for (int d = 1; d < 64; d <<= 1) { u32 n = __shfl_up(x, (unsigned)d, 64); if (lane >= d) x += n; }
    if (lane == 63) wsum[wid] = x;
    u32 exwave = x - run;
    __syncthreads();
    if (tid == 0) {
        u32 rr = 0;
        for (int w = 0; w < P1T / 64; ++w) { u32 s = wsum[w]; wsum[w] = rr; rr += s; }
    }
    __syncthreads();
    const u32 tbase = (u32)tilebase + wsum[wid] + exwave;
#pragma unroll
    for (int j = 0; j < 8; ++j) {
        u32 bs = tbase + cch[j];
        dir[t * FB_NBCK + b0 + j] = bs;
        hist[b0 + j] = bs;
    }
    __syncthreads();

    for (int it = 0; it < FB_TILE / 4 / P1T; ++it) {
        int gi = tid + it * P1T;
        int4 m = m4[g4base + gi];
        float4 v = v4[g4base + gi];
        int e0 = tilebase + gi * 4;
        u32 ob = ((u32)(e0 >> 23)) << 24;
        u32 c0 = (u32)(e0 & 63);
        u32 tg, p;
        tg = ob + (u32)(m.x & ~63) + c0 + 0; p = atomicAdd(&hist[tg >> RSH], 1u);
        wval[p] = v.x; widx[p] = (u16)(tg & (RSLOTS - 1));
        tg = ob + (u32)(m.y & ~63) + c0 + 1; p = atomicAdd(&hist[tg >> RSH], 1u);
        wval[p] = v.y; widx[p] = (u16)(tg & (RSLOTS - 1));
        tg = ob + (u32)(m.z & ~63) + c0 + 2; p = atomicAdd(&hist[tg >> RSH], 1u);
        wval[p] = v.z; widx[p] = (u16)(tg & (RSLOTS - 1));
        tg = ob + (u32)(m.w & ~63) + c0 + 3; p = atomicAdd(&hist[tg >> RSH], 1u);
        wval[p] = v.w; widx[p] = (u16)(tg & (RSLOTS - 1));
    }
}

__global__ __launch_bounds__(P2T) void p2_acc(const float* __restrict__ wval,
                                              const u16* __restrict__ widx,
                                              const u32* __restrict__ dir,
                                              float* __restrict__ out)
{
    __shared__ float acc[RSLOTS];
    __shared__ u32 sbase[FB_NTILES];
    __shared__ u32 send[FB_NTILES];
    const int tid = threadIdx.x;
    const int lane = tid & 63;
    const int wid = tid >> 6;
    const int g = blockIdx.x;

    for (int i = tid; i < RSLOTS; i += P2T) acc[i] = 0.f;
    if (tid < FB_NTILES) {
        sbase[tid] = dir[tid * FB_NBCK + g];
        send[tid] = (g == FB_NBCK - 1) ? (u32)((tid + 1) * FB_TILE) : dir[tid * FB_NBCK + g + 1];
    }
    __syncthreads();

    for (int t = wid; t < FB_NTILES; t += P2T / 64) {
        u32 base = sbase[t];
        u32 end = send[t];
        for (u32 k = base + (u32)lane; k < end; k += 64) {
            atomicAdd(&acc[widx[k]], wval[k]);
        }
    }
    __syncthreads();

    float4* out4 = (float4*)out;
    const float4* a4 = (const float4*)acc;
    const long long ob4 = (long long)g << (RSH - 2);
    for (int i = tid; i < RSLOTS / 4; i += P2T) out4[ob4 + i] = a4[i];
}

__global__ __launch_bounds__(256) void unmaxpool_scatter(
    const float* __restrict__ in, const int* __restrict__ mask,
    float* __restrict__ out)
{
    const long long n4 = N_IN / 4;
    long long gidx = (long long)blockIdx.x * blockDim.x + threadIdx.x;
    const long long stride = (long long)gridDim.x * blockDim.x;
    for (; gidx < n4; gidx += stride) {
        float4 v = reinterpret_cast<const float4*>(in)[gidx];
        int4 m = reinterpret_cast<const int4*>(mask)[gidx];
        long long i0 = gidx * 4;
        u32 ob = ((u32)(i0 >> 23)) << 24;
        u32 c0 = (u32)(i0 & 63);
        atomicAdd(&out[ob + (u32)(m.x & ~63) + c0 + 0], v.x);
        atomicAdd(&out[ob + (u32)(m.y & ~63) + c0 + 1], v.y);
        atomicAdd(&out[ob + (u32)(m.z & ~63) + c0 + 2], v.z);
        atomicAdd(&out[ob + (u32)(m.w & ~63) + c0 + 3], v.w);
    }
}

extern "C" void kernel_launch(void* const* d_in, const int* in_sizes, int n_in,
                              void* d_out, int out_size, void* d_ws, size_t ws_size,
                              hipStream_t stream) {
    const float* in = (const float*)d_in[0];
    const int* mask = (const int*)d_in[1];
    float* out = (float*)d_out;
    char* ws = (char*)d_ws;

    if (d_ws != nullptr && ws_size >= WS2_NEED) {
        u32* idxA = (u32*)(ws + OFF2_IDXA);
        float* valA = (float*)(ws + OFF2_VALA);
        u16* idxB = (u16*)(ws + OFF2_IDXB);
        float* valB = (float*)(ws + OFF2_VALB);
        u32* dirA = (u32*)(ws + OFF2_DIRA);
        u32* dirF = (u32*)(ws + OFF2_DIRF);
        u32* rangeSum = (u32*)(ws + OFF2_RS);
        u32* baseB = (u32*)(ws + OFF2_BB);
        u32* totalF = (u32*)(ws + OFF2_TOT);
        u32* fineBase = (u32*)(ws + OFF2_FB);

        passA<<<NTILE, A_T, 0, stream>>>(in, mask, idxA, valA, dirA, dirF);
        mid1<<<NFG / 256, 256, 0, stream>>>(dirF, rangeSum, totalF);
        mid2<<<1, 1024, 0, stream>>>(totalF, rangeSum, fineBase, baseB);
        passB<<<NC * NR, 512, 0, stream>>>(idxA, valA, dirA, baseB, idxB, valB);
        passC<<<NFG, 1024, 0, stream>>>(idxB, valB, fineBase, out);
    } else if (d_ws != nullptr && ws_size >= WS_NEED) {
        float* wval = (float*)(ws + OFF_VAL);
        u16* widx = (u16*)(ws + OFF_IDX);
        u32* dir = (u32*)(ws + OFF_DIR);
        p1_bin<<<FB_NTILES, P1T, 0, stream>>>(in, mask, wval, widx, dir);
        p2_acc<<<FB_NBCK, P2T, 0, stream>>>(wval, widx, dir, out);
    } else {
        hipMemsetAsync(out, 0, (size_t)out_size * sizeof(float), stream);
        unmaxpool_scatter<<<2048, 256, 0, stream>>>(in, mask, out);
    }
}

// Round 4
// 1107.080 us; speedup vs baseline: 1.6867x; 1.6867x over previous
//
#include <hip/hip_runtime.h>

// UnMaxPoolWithArgmax, two-pass fused counting-sort:
//   passA: per 4096-elem sub-batch (one image batch b each), LDS-sort records
//          by 128 in-batch coarse buckets (tg>>17 & 127), flush contiguous u64
//          records (rel17<<32 | valbits) + u16 chunk-offset directory. Write amp ~1.
//   passC: one block per global coarse region c (1024 regions of 2^17 slots);
//          4 window sweeps of a 2^15-slot LDS accumulator over the block's
//          ~0.5MB record set (sweeps 2-4 are L2/L3 hits); coalesced float4 out.
// target tg = (b<<24) | (mask & ~63) | c0   (27 bits); out covered fully (no memset).

typedef unsigned int u32;
typedef unsigned short u16;
typedef unsigned long long u64;

constexpr long long N_IN = 1LL << 26;     // 67,108,864 elements
constexpr int SBS  = 4096;                // elements per sub-batch
constexpr int NSB  = (int)(N_IN / SBS);   // 16384
constexpr int LC   = 128;                 // in-batch coarse buckets (tg>>17 & 127)
constexpr int NREG = 1024;                // global regions (8 batches * 128)
constexpr int RSH  = 15;                  // LDS window = 2^15 slots (128 KiB)
constexpr int RSLOTS = 1 << RSH;
constexpr int SB_PER_B = 2048;            // sub-batches per image batch

// ---------------- workspace (fused path) ----------------
constexpr size_t OFF_RECA  = 0;                                  // u64[2^26] = 512 MiB
constexpr size_t OFF_DIR16 = (size_t)N_IN * 8;                   // u16[NSB*LC] = 4 MiB
constexpr size_t WS_FUSED  = OFF_DIR16 + (size_t)NSB * LC * 2;   // ~541 MB

// ============================ passA ============================
__global__ __launch_bounds__(512) void passA(const float* __restrict__ in,
                                             const int* __restrict__ mask,
                                             u64* __restrict__ recA,
                                             u16* __restrict__ dirA16)
{
    __shared__ u32 cur[LC];
    __shared__ u64 sRec[SBS];     // 32 KiB
    const int tid = threadIdx.x;
    const int sb  = blockIdx.x;
    const int e0  = sb * SBS + tid * 8;

    const int4*   m4 = (const int4*)mask + (e0 >> 2);
    const float4* v4 = (const float4*)in + (e0 >> 2);
    int4 ma = m4[0], mb = m4[1];
    float4 va = v4[0], vb = v4[1];
    const u32 bb = ((u32)(e0 >> 23)) << 24;     // batch bits (HWC = 2^23)
    const u32 c0 = (u32)(e0 & 63);

    u32 tg[8]; float vv[8];
    tg[0] = bb + (((u32)ma.x) & ~63u) + c0 + 0; vv[0] = va.x;
    tg[1] = bb + (((u32)ma.y) & ~63u) + c0 + 1; vv[1] = va.y;
    tg[2] = bb + (((u32)ma.z) & ~63u) + c0 + 2; vv[2] = va.z;
    tg[3] = bb + (((u32)ma.w) & ~63u) + c0 + 3; vv[3] = va.w;
    tg[4] = bb + (((u32)mb.x) & ~63u) + c0 + 4; vv[4] = vb.x;
    tg[5] = bb + (((u32)mb.y) & ~63u) + c0 + 5; vv[5] = vb.y;
    tg[6] = bb + (((u32)mb.z) & ~63u) + c0 + 6; vv[6] = vb.z;
    tg[7] = bb + (((u32)mb.w) & ~63u) + c0 + 7; vv[7] = vb.w;

    if (tid < LC) cur[tid] = 0;
    __syncthreads();
#pragma unroll
    for (int j = 0; j < 8; ++j) atomicAdd(&cur[(tg[j] >> 17) & 127u], 1u);
    __syncthreads();

    // exclusive scan of 128 counters by wave 0 (2 per lane)
    if (tid < 64) {
        u32 a  = cur[2 * tid];
        u32 b2 = cur[2 * tid + 1];
        u32 sum = a + b2;
        u32 s = sum;
#pragma unroll
        for (int d = 1; d < 64; d <<= 1) {
            u32 n = __shfl_up(s, (unsigned)d, 64);
            if (tid >= d) s += n;
        }
        u32 ex = s - sum;
        cur[2 * tid]     = ex;
        cur[2 * tid + 1] = ex + a;
        dirA16[(size_t)sb * LC + 2 * tid]     = (u16)ex;
        dirA16[(size_t)sb * LC + 2 * tid + 1] = (u16)(ex + a);
    }
    __syncthreads();

#pragma unroll
    for (int j = 0; j < 8; ++j) {
        u32 p = atomicAdd(&cur[(tg[j] >> 17) & 127u], 1u);
        sRec[p] = ((u64)(tg[j] & 0x1FFFFu) << 32) | (u64)__float_as_uint(vv[j]);
    }
    __syncthreads();
#pragma unroll
    for (int k = 0; k < 8; ++k) {
        int i = tid + k * 512;
        recA[(size_t)sb * SBS + i] = sRec[i];   // contiguous u64 flush
    }
}

// ============================ passC ============================
__global__ __launch_bounds__(1024) void passC(const u64* __restrict__ recA,
                                              const u16* __restrict__ dirA16,
                                              float* __restrict__ out)
{
    __shared__ float acc[RSLOTS];     // 128 KiB
    __shared__ u32 cSrc[SB_PER_B];    // 8 KiB
    __shared__ u16 cLen[SB_PER_B];    // 4 KiB
    const int tid = threadIdx.x;
    const int c   = blockIdx.x;       // global region 0..1023
    const int bb  = c >> 7;
    const int lc  = c & 127;

    for (int s = tid; s < SB_PER_B; s += 1024) {
        const int sb = bb * SB_PER_B + s;
        u32 o0 = dirA16[(size_t)sb * LC + lc];
        u32 o1 = (lc < LC - 1) ? (u32)dirA16[(size_t)sb * LC + lc + 1] : (u32)SBS;
        cSrc[s] = (u32)sb * SBS + o0;
        cLen[s] = (u16)(o1 - o0);
    }

    const int wid  = tid >> 6;
    const int lane = tid & 63;
    const int half = lane >> 5;       // 2 chunks per wave (32 lanes each)
    const int sl   = lane & 31;

    for (int w = 0; w < 4; ++w) {
        __syncthreads();              // prev flush done before re-zero
        for (int i = tid; i < RSLOTS; i += 1024) acc[i] = 0.f;
        __syncthreads();
        for (int s2 = wid * 2 + half; s2 < SB_PER_B; s2 += 32) {
            u32 src = cSrc[s2];
            int len = (int)cLen[s2];
            for (int off = sl; off < len; off += 32) {
                u64 rec = recA[src + off];
                u32 rel = (u32)(rec >> 32);
                if ((int)(rel >> RSH) == w)
                    atomicAdd(&acc[rel & (RSLOTS - 1)], __uint_as_float((u32)rec));
            }
        }
        __syncthreads();
        float4* o4 = (float4*)out + ((((size_t)c << 17) + ((size_t)w << RSH)) >> 2);
        const float4* a4 = (const float4*)acc;
        for (int i = tid; i < RSLOTS / 4; i += 1024) o4[i] = a4[i];
    }
}

// ===================== fallback 1: round-2 two-phase binning =====================
constexpr int FB_NBCK = 4096;
constexpr int FB_TILE = 1 << 17;
constexpr int FB_NTILES = (int)(N_IN / FB_TILE);   // 512
constexpr int P1T = 512;
constexpr int P2T = 1024;
constexpr size_t OFF_VAL = 0;
constexpr size_t OFF_IDX = (size_t)N_IN * 4;
constexpr size_t OFF_DIR = OFF_IDX + (size_t)N_IN * 2;
constexpr size_t WS_BIN  = OFF_DIR + (size_t)FB_NTILES * FB_NBCK * 4;

__global__ __launch_bounds__(P1T) void p1_bin(const float* __restrict__ in,
                                              const int* __restrict__ mask,
                                              float* __restrict__ wval,
                                              u16* __restrict__ widx,
                                              u32* __restrict__ dir)
{
    __shared__ u32 hist[FB_NBCK];
    __shared__ u32 wsum[P1T / 64];
    const int tid = threadIdx.x;
    const int lane = tid & 63;
    const int wid = tid >> 6;
    const int t = blockIdx.x;
    const int tilebase = t * FB_TILE;
    const int g4base = tilebase >> 2;

    for (int i = tid; i < FB_NBCK; i += P1T) hist[i] = 0;
    __syncthreads();

    const int4* m4 = (const int4*)mask;
    const float4* v4 = (const float4*)in;

    for (int it = 0; it < FB_TILE / 4 / P1T; ++it) {
        int gi = tid + it * P1T;
        int4 m = m4[g4base + gi];
        int e0 = tilebase + gi * 4;
        u32 ob = ((u32)(e0 >> 23)) << 24;
        atomicAdd(&hist[(ob + (u32)(m.x & ~63)) >> RSH], 1u);
        atomicAdd(&hist[(ob + (u32)(m.y & ~63)) >> RSH], 1u);
        atomicAdd(&hist[(ob + (u32)(m.z & ~63)) >> RSH], 1u);
        atomicAdd(&hist[(ob + (u32)(m.w & ~63)) >> RSH], 1u);
    }
    __syncthreads();

    u32 cch[8];
    u32 run = 0;
    const int b0 = tid * (FB_NBCK / P1T);
#pragma unroll
    for (int j = 0; j < 8; ++j) { u32 x = hist[b0 + j]; cch[j] = run; run += x; }
    u32 x = run;
#pragma unroll
    for (int d = 1; d < 64; d <<= 1) { u32 n = __shfl_up(x, (unsigned)d, 64); if (lane >= d) x += n; }
    if (lane == 63) wsum[wid] = x;
    u32 exwave = x - run;
    __syncthreads();
    if (tid == 0) {
        u32 rr = 0;
        for (int w = 0; w < P1T / 64; ++w) { u32 s = wsum[w]; wsum[w] = rr; rr += s; }
    }
    __syncthreads();
    const u32 tbase = (u32)tilebase + wsum[wid] + exwave;
#pragma unroll
    for (int j = 0; j < 8; ++j) {
        u32 bs = tbase + cch[j];
        dir[t * FB_NBCK + b0 + j] = bs;
        hist[b0 + j] = bs;
    }
    __syncthreads();

    for (int it = 0; it < FB_TILE / 4 / P1T; ++it) {
        int gi = tid + it * P1T;
        int4 m = m4[g4base + gi];
        float4 v = v4[g4base + gi];
        int e0 = tilebase + gi * 4;
        u32 ob = ((u32)(e0 >> 23)) << 24;
        u32 c0 = (u32)(e0 & 63);
        u32 tg, p;
        tg = ob + (u32)(m.x & ~63) + c0 + 0; p = atomicAdd(&hist[tg >> RSH], 1u);
        wval[p] = v.x; widx[p] = (u16)(tg & (RSLOTS - 1));
        tg = ob + (u32)(m.y & ~63) + c0 + 1; p = atomicAdd(&hist[tg >> RSH], 1u);
        wval[p] = v.y; widx[p] = (u16)(tg & (RSLOTS - 1));
        tg = ob + (u32)(m.z & ~63) + c0 + 2; p = atomicAdd(&hist[tg >> RSH], 1u);
        wval[p] = v.z; widx[p] = (u16)(tg & (RSLOTS - 1));
        tg = ob + (u32)(m.w & ~63) + c0 + 3; p = atomicAdd(&hist[tg >> RSH], 1u);
        wval[p] = v.w; widx[p] = (u16)(tg & (RSLOTS - 1));
    }
}

__global__ __launch_bounds__(P2T) void p2_acc(const float* __restrict__ wval,
                                              const u16* __restrict__ widx,
                                              const u32* __restrict__ dir,
                                              float* __restrict__ out)
{
    __shared__ float acc[RSLOTS];
    __shared__ u32 sbase[FB_NTILES];
    __shared__ u32 send[FB_NTILES];
    const int tid = threadIdx.x;
    const int lane = tid & 63;
    const int wid = tid >> 6;
    const int g = blockIdx.x;

    for (int i = tid; i < RSLOTS; i += P2T) acc[i] = 0.f;
    if (tid < FB_NTILES) {
        sbase[tid] = dir[tid * FB_NBCK + g];
        send[tid] = (g == FB_NBCK - 1) ? (u32)((tid + 1) * FB_TILE) : dir[tid * FB_NBCK + g + 1];
    }
    __syncthreads();

    for (int t = wid; t < FB_NTILES; t += P2T / 64) {
        u32 base = sbase[t];
        u32 end = send[t];
        for (u32 k = base + (u32)lane; k < end; k += 64) {
            atomicAdd(&acc[widx[k]], wval[k]);
        }
    }
    __syncthreads();

    float4* out4 = (float4*)out;
    const float4* a4 = (const float4*)acc;
    const long long ob4 = (long long)g << (RSH - 2);
    for (int i = tid; i < RSLOTS / 4; i += P2T) out4[ob4 + i] = a4[i];
}

// ===================== fallback 2: direct atomic scatter =====================
__global__ __launch_bounds__(256) void unmaxpool_scatter(
    const float* __restrict__ in, const int* __restrict__ mask,
    float* __restrict__ out)
{
    const long long n4 = N_IN / 4;
    long long gidx = (long long)blockIdx.x * blockDim.x + threadIdx.x;
    const long long stride = (long long)gridDim.x * blockDim.x;
    for (; gidx < n4; gidx += stride) {
        float4 v = reinterpret_cast<const float4*>(in)[gidx];
        int4 m = reinterpret_cast<const int4*>(mask)[gidx];
        long long i0 = gidx * 4;
        u32 ob = ((u32)(i0 >> 23)) << 24;
        u32 c0 = (u32)(i0 & 63);
        atomicAdd(&out[ob + (u32)(m.x & ~63) + c0 + 0], v.x);
        atomicAdd(&out[ob + (u32)(m.y & ~63) + c0 + 1], v.y);
        atomicAdd(&out[ob + (u32)(m.z & ~63) + c0 + 2], v.z);
        atomicAdd(&out[ob + (u32)(m.w & ~63) + c0 + 3], v.w);
    }
}

extern "C" void kernel_launch(void* const* d_in, const int* in_sizes, int n_in,
                              void* d_out, int out_size, void* d_ws, size_t ws_size,
                              hipStream_t stream) {
    const float* in = (const float*)d_in[0];
    const int* mask = (const int*)d_in[1];
    float* out = (float*)d_out;
    char* ws = (char*)d_ws;

    if (d_ws != nullptr && ws_size >= WS_FUSED) {
        u64* recA   = (u64*)(ws + OFF_RECA);
        u16* dirA16 = (u16*)(ws + OFF_DIR16);
        passA<<<NSB, 512, 0, stream>>>(in, mask, recA, dirA16);
        passC<<<NREG, 1024, 0, stream>>>(recA, dirA16, out);
    } else if (d_ws != nullptr && ws_size >= WS_BIN) {
        float* wval = (float*)(ws + OFF_VAL);
        u16* widx = (u16*)(ws + OFF_IDX);
        u32* dir = (u32*)(ws + OFF_DIR);
        p1_bin<<<FB_NTILES, P1T, 0, stream>>>(in, mask, wval, widx, dir);
        p2_acc<<<FB_NBCK, P2T, 0, stream>>>(wval, widx, dir, out);
    } else {
        hipMemsetAsync(out, 0, (size_t)out_size * sizeof(float), stream);
        unmaxpool_scatter<<<2048, 256, 0, stream>>>(in, mask, out);
    }
}

// Round 5
// 738.494 us; speedup vs baseline: 2.5285x; 1.4991x over previous
//
#include <hip/hip_runtime.h>

// UnMaxPoolWithArgmax, two-pass counting-sort at window granularity:
//   passA: per 8192-elem sub-batch (one image batch b each), LDS-sort records
//          by 512 in-batch window buckets ((tg>>15)&511); flush contiguous
//          u64 records (rel15<<32 | valbits) + u16 offset directory (amp ~1).
//   tposeD: transpose directory to window-major (8 MB, trivial).
//   passC: one block per 2^15-slot window (4096); single sweep: gather 1024
//          ~128B chunks coalesced, LDS atomicAdd once per record, one 128 KB
//          coalesced store. Covers whole output (no memset).
// target tg = (b<<24) | (mask & ~63) | c0 (27 bits); window = tg>>15 (4096).

typedef unsigned int u32;
typedef unsigned short u16;
typedef unsigned long long u64;

constexpr long long N_IN = 1LL << 26;      // 67,108,864 elements
constexpr int SBS   = 8192;                // elements per sub-batch
constexpr int NSB   = (int)(N_IN / SBS);   // 8192 sub-batches
constexpr int NBKT  = 512;                 // in-batch window buckets
constexpr int NWIN  = 4096;                // global windows (8 batches * 512)
constexpr int RSH   = 15;                  // window = 2^15 slots (128 KiB)
constexpr int RSLOTS = 1 << RSH;
constexpr int SB_PER_B = 1024;             // sub-batches per image batch

// ---------------- workspace ----------------
constexpr size_t OFF_RECA = 0;                                   // u64[2^26] = 512 MiB
constexpr size_t OFF_DIR  = (size_t)N_IN * 8;                    // u16[NSB*NBKT] = 8 MiB
constexpr size_t OFF_DIRT = OFF_DIR + (size_t)NSB * NBKT * 2;    // u16[NWIN*SB_PER_B] = 8 MiB
constexpr size_t WS_FUSED = OFF_DIRT + (size_t)NWIN * SB_PER_B * 2;  // ~528 MiB

// ============================ passA ============================
__global__ __launch_bounds__(512) void passA(const float* __restrict__ in,
                                             const int* __restrict__ mask,
                                             u64* __restrict__ recA,
                                             u16* __restrict__ dir)
{
    __shared__ u32 cur[NBKT];      // hist -> starts -> cursors
    __shared__ u32 wsum[8];
    __shared__ u64 sRec[SBS];      // 64 KiB
    const int tid = threadIdx.x;
    const int sb  = blockIdx.x;
    const int e0  = sb * SBS + tid * 16;

    const int4*   m4 = (const int4*)mask + (e0 >> 2);
    const float4* v4 = (const float4*)in + (e0 >> 2);
    int4 m0 = m4[0], m1 = m4[1], m2 = m4[2], m3 = m4[3];
    float4 va = v4[0], vb = v4[1], vc = v4[2], vd = v4[3];
    const u32 bbits = ((u32)(e0 >> 23)) << 24;   // batch bits (HWC = 2^23)
    const u32 c0 = (u32)(e0 & 63);

    u32 tg[16]; float vv[16];
    tg[ 0] = bbits + (((u32)m0.x) & ~63u) + c0 +  0; vv[ 0] = va.x;
    tg[ 1] = bbits + (((u32)m0.y) & ~63u) + c0 +  1; vv[ 1] = va.y;
    tg[ 2] = bbits + (((u32)m0.z) & ~63u) + c0 +  2; vv[ 2] = va.z;
    tg[ 3] = bbits + (((u32)m0.w) & ~63u) + c0 +  3; vv[ 3] = va.w;
    tg[ 4] = bbits + (((u32)m1.x) & ~63u) + c0 +  4; vv[ 4] = vb.x;
    tg[ 5] = bbits + (((u32)m1.y) & ~63u) + c0 +  5; vv[ 5] = vb.y;
    tg[ 6] = bbits + (((u32)m1.z) & ~63u) + c0 +  6; vv[ 6] = vb.z;
    tg[ 7] = bbits + (((u32)m1.w) & ~63u) + c0 +  7; vv[ 7] = vb.w;
    tg[ 8] = bbits + (((u32)m2.x) & ~63u) + c0 +  8; vv[ 8] = vc.x;
    tg[ 9] = bbits + (((u32)m2.y) & ~63u) + c0 +  9; vv[ 9] = vc.y;
    tg[10] = bbits + (((u32)m2.z) & ~63u) + c0 + 10; vv[10] = vc.z;
    tg[11] = bbits + (((u32)m2.w) & ~63u) + c0 + 11; vv[11] = vc.w;
    tg[12] = bbits + (((u32)m3.x) & ~63u) + c0 + 12; vv[12] = vd.x;
    tg[13] = bbits + (((u32)m3.y) & ~63u) + c0 + 13; vv[13] = vd.y;
    tg[14] = bbits + (((u32)m3.z) & ~63u) + c0 + 14; vv[14] = vd.z;
    tg[15] = bbits + (((u32)m3.w) & ~63u) + c0 + 15; vv[15] = vd.w;

    cur[tid] = 0;
    __syncthreads();
#pragma unroll
    for (int j = 0; j < 16; ++j) atomicAdd(&cur[(tg[j] >> RSH) & (NBKT - 1)], 1u);
    __syncthreads();

    // exclusive scan of 512 counters (one per thread)
    {
        const int lane = tid & 63;
        const int wid  = tid >> 6;
        u32 x = cur[tid];
        u32 s = x;
#pragma unroll
        for (int d = 1; d < 64; d <<= 1) {
            u32 n = __shfl_up(s, (unsigned)d, 64);
            if (lane >= d) s += n;
        }
        if (lane == 63) wsum[wid] = s;
        u32 exw = s - x;
        __syncthreads();
        if (tid == 0) {
            u32 run = 0;
#pragma unroll
            for (int w = 0; w < 8; ++w) { u32 t2 = wsum[w]; wsum[w] = run; run += t2; }
        }
        __syncthreads();
        u32 start = wsum[wid] + exw;
        dir[(size_t)sb * NBKT + tid] = (u16)start;
        cur[tid] = start;              // cursor
    }
    __syncthreads();

#pragma unroll
    for (int j = 0; j < 16; ++j) {
        u32 p = atomicAdd(&cur[(tg[j] >> RSH) & (NBKT - 1)], 1u);
        sRec[p] = ((u64)(tg[j] & (RSLOTS - 1)) << 32) | (u64)__float_as_uint(vv[j]);
    }
    __syncthreads();
#pragma unroll
    for (int k = 0; k < 16; ++k) {
        int i = tid + k * 512;
        recA[(size_t)sb * SBS + i] = sRec[i];    // contiguous u64 flush
    }
}

// ============================ directory transpose ============================
// dir[bb*1024+sb][512 lb] -> dirT[bb*512+lb][1024 sb]; 64x64 u16 tiles.
__global__ __launch_bounds__(256) void tposeD(const u16* __restrict__ dir,
                                              u16* __restrict__ dirT)
{
    __shared__ u16 t[64][65];
    const int tx = threadIdx.x;        // 0..63
    const int ty = threadIdx.y;        // 0..3
    const int bb = blockIdx.z;
    const int sb0 = blockIdx.x * 64;   // 16 tiles
    const int lb0 = blockIdx.y * 64;   // 8 tiles
#pragma unroll
    for (int k = 0; k < 16; ++k) {
        int row = k * 4 + ty;          // sb within tile
        t[row][tx] = dir[((size_t)(bb * SB_PER_B + sb0 + row)) * NBKT + lb0 + tx];
    }
    __syncthreads();
#pragma unroll
    for (int k = 0; k < 16; ++k) {
        int row = k * 4 + ty;          // lb within tile
        dirT[((size_t)(bb * NBKT + lb0 + row)) * SB_PER_B + sb0 + tx] = t[tx][row];
    }
}

// ============================ passC ============================
__global__ __launch_bounds__(1024) void passC(const u64* __restrict__ recA,
                                              const u16* __restrict__ dirT,
                                              float* __restrict__ out)
{
    __shared__ float acc[RSLOTS];      // 128 KiB
    __shared__ u32 cSrc[SB_PER_B];     // 4 KiB
    __shared__ u16 cLen[SB_PER_B];     // 2 KiB
    const int tid = threadIdx.x;
    const int bid = blockIdx.x;
    const int w   = ((bid & 7) << 9) | (bid >> 3);   // XCD-chunked bijective swizzle
    const int bb  = w >> 9;
    const int lb  = w & (NBKT - 1);

    {   // chunk table: two contiguous directory rows
        u32 st = dirT[(size_t)w * SB_PER_B + tid];
        u32 en = (lb == NBKT - 1) ? (u32)SBS : (u32)dirT[(size_t)(w + 1) * SB_PER_B + tid];
        cSrc[tid] = (u32)(bb * SB_PER_B + tid) * (u32)SBS + st;
        cLen[tid] = (u16)(en - st);
    }
    for (int i = tid; i < RSLOTS; i += 1024) acc[i] = 0.f;
    __syncthreads();

    const int g  = tid >> 4;           // 64 groups of 16 lanes
    const int gl = tid & 15;
    for (int s2 = g; s2 < SB_PER_B; s2 += 64) {
        u32 src = cSrc[s2];
        int len = (int)cLen[s2];
        for (int off = gl; off < len; off += 16) {
            u64 rec = recA[src + off];
            atomicAdd(&acc[(u32)(rec >> 32)], __uint_as_float((u32)rec));
        }
    }
    __syncthreads();

    float4* o4 = (float4*)out + ((size_t)w << (RSH - 2));
    const float4* a4 = (const float4*)acc;
#pragma unroll
    for (int i = tid; i < RSLOTS / 4; i += 1024) o4[i] = a4[i];
}

// ===================== fallback: direct atomic scatter =====================
__global__ __launch_bounds__(256) void unmaxpool_scatter(
    const float* __restrict__ in, const int* __restrict__ mask,
    float* __restrict__ out)
{
    const long long n4 = N_IN / 4;
    long long gidx = (long long)blockIdx.x * blockDim.x + threadIdx.x;
    const long long stride = (long long)gridDim.x * blockDim.x;
    for (; gidx < n4; gidx += stride) {
        float4 v = reinterpret_cast<const float4*>(in)[gidx];
        int4 m = reinterpret_cast<const int4*>(mask)[gidx];
        long long i0 = gidx * 4;
        u32 ob = ((u32)(i0 >> 23)) << 24;
        u32 c0 = (u32)(i0 & 63);
        atomicAdd(&out[ob + (u32)(m.x & ~63) + c0 + 0], v.x);
        atomicAdd(&out[ob + (u32)(m.y & ~63) + c0 + 1], v.y);
        atomicAdd(&out[ob + (u32)(m.z & ~63) + c0 + 2], v.z);
        atomicAdd(&out[ob + (u32)(m.w & ~63) + c0 + 3], v.w);
    }
}

extern "C" void kernel_launch(void* const* d_in, const int* in_sizes, int n_in,
                              void* d_out, int out_size, void* d_ws, size_t ws_size,
                              hipStream_t stream) {
    const float* in = (const float*)d_in[0];
    const int* mask = (const int*)d_in[1];
    float* out = (float*)d_out;
    char* ws = (char*)d_ws;

    if (d_ws != nullptr && ws_size >= WS_FUSED) {
        u64* recA = (u64*)(ws + OFF_RECA);
        u16* dir  = (u16*)(ws + OFF_DIR);
        u16* dirT = (u16*)(ws + OFF_DIRT);
        passA<<<NSB, 512, 0, stream>>>(in, mask, recA, dir);
        tposeD<<<dim3(16, 8, 8), dim3(64, 4), 0, stream>>>(dir, dirT);
        passC<<<NWIN, 1024, 0, stream>>>(recA, dirT, out);
    } else {
        hipMemsetAsync(out, 0, (size_t)out_size * sizeof(float), stream);
        unmaxpool_scatter<<<2048, 256, 0, stream>>>(in, mask, out);
    }
}

// Round 7
// 673.429 us; speedup vs baseline: 2.7728x; 1.0966x over previous
//
#include <hip/hip_runtime.h>

// UnMaxPoolWithArgmax, two-pass counting-sort at window granularity:
//   passA: per 8192-elem sub-batch (one image batch b each), LDS-sort records
//          by 512 in-batch window buckets ((tg>>15)&511); flush contiguous
//          u64 records (rel15<<32 | valbits) + u16 offset directory (amp ~1).
//   tposeD: transpose directory to window-major (8 MB, trivial).
//   passC: one block per 2^15-slot window (4096); single sweep with 4-deep
//          MLP gather (2 chunks x 2 predicated loads per 16-lane group),
//          LDS atomicAdd once per record, nontemporal 128 KB store.
// target tg = (b<<24) | (mask & ~63) | c0 (27 bits); window = tg>>15 (4096).

typedef unsigned int u32;
typedef unsigned short u16;
typedef unsigned long long u64;

// clang ext-vector types (valid for __builtin_nontemporal_load/store,
// unlike HIP_vector_type wrappers)
typedef int   iv4 __attribute__((ext_vector_type(4)));
typedef float fv4 __attribute__((ext_vector_type(4)));

constexpr long long N_IN = 1LL << 26;      // 67,108,864 elements
constexpr int SBS   = 8192;                // elements per sub-batch
constexpr int NSB   = (int)(N_IN / SBS);   // 8192 sub-batches
constexpr int NBKT  = 512;                 // in-batch window buckets
constexpr int NWIN  = 4096;                // global windows (8 batches * 512)
constexpr int RSH   = 15;                  // window = 2^15 slots (128 KiB)
constexpr int RSLOTS = 1 << RSH;
constexpr int SB_PER_B = 1024;             // sub-batches per image batch

// ---------------- workspace ----------------
constexpr size_t OFF_RECA = 0;                                   // u64[2^26] = 512 MiB
constexpr size_t OFF_DIR  = (size_t)N_IN * 8;                    // u16[NSB*NBKT] = 8 MiB
constexpr size_t OFF_DIRT = OFF_DIR + (size_t)NSB * NBKT * 2;    // u16[NWIN*SB_PER_B] = 8 MiB
constexpr size_t WS_FUSED = OFF_DIRT + (size_t)NWIN * SB_PER_B * 2;  // ~528 MiB

// ============================ passA ============================
__global__ __launch_bounds__(512) void passA(const float* __restrict__ in,
                                             const int* __restrict__ mask,
                                             u64* __restrict__ recA,
                                             u16* __restrict__ dir)
{
    __shared__ u32 cur[NBKT];      // hist -> starts -> cursors
    __shared__ u32 wsum[8];
    __shared__ u64 sRec[SBS];      // 64 KiB
    const int tid = threadIdx.x;
    const int sb  = blockIdx.x;
    const int e0  = sb * SBS + tid * 16;

    const iv4* m4 = (const iv4*)mask + (e0 >> 2);
    const fv4* v4 = (const fv4*)in + (e0 >> 2);
    iv4 m0 = __builtin_nontemporal_load(m4 + 0);
    iv4 m1 = __builtin_nontemporal_load(m4 + 1);
    iv4 m2 = __builtin_nontemporal_load(m4 + 2);
    iv4 m3 = __builtin_nontemporal_load(m4 + 3);
    fv4 va = __builtin_nontemporal_load(v4 + 0);
    fv4 vb = __builtin_nontemporal_load(v4 + 1);
    fv4 vc = __builtin_nontemporal_load(v4 + 2);
    fv4 vd = __builtin_nontemporal_load(v4 + 3);
    const u32 bbits = ((u32)(e0 >> 23)) << 24;   // batch bits (HWC = 2^23)
    const u32 c0 = (u32)(e0 & 63);

    u32 tg[16]; float vv[16];
    tg[ 0] = bbits + (((u32)m0.x) & ~63u) + c0 +  0; vv[ 0] = va.x;
    tg[ 1] = bbits + (((u32)m0.y) & ~63u) + c0 +  1; vv[ 1] = va.y;
    tg[ 2] = bbits + (((u32)m0.z) & ~63u) + c0 +  2; vv[ 2] = va.z;
    tg[ 3] = bbits + (((u32)m0.w) & ~63u) + c0 +  3; vv[ 3] = va.w;
    tg[ 4] = bbits + (((u32)m1.x) & ~63u) + c0 +  4; vv[ 4] = vb.x;
    tg[ 5] = bbits + (((u32)m1.y) & ~63u) + c0 +  5; vv[ 5] = vb.y;
    tg[ 6] = bbits + (((u32)m1.z) & ~63u) + c0 +  6; vv[ 6] = vb.z;
    tg[ 7] = bbits + (((u32)m1.w) & ~63u) + c0 +  7; vv[ 7] = vb.w;
    tg[ 8] = bbits + (((u32)m2.x) & ~63u) + c0 +  8; vv[ 8] = vc.x;
    tg[ 9] = bbits + (((u32)m2.y) & ~63u) + c0 +  9; vv[ 9] = vc.y;
    tg[10] = bbits + (((u32)m2.z) & ~63u) + c0 + 10; vv[10] = vc.z;
    tg[11] = bbits + (((u32)m2.w) & ~63u) + c0 + 11; vv[11] = vc.w;
    tg[12] = bbits + (((u32)m3.x) & ~63u) + c0 + 12; vv[12] = vd.x;
    tg[13] = bbits + (((u32)m3.y) & ~63u) + c0 + 13; vv[13] = vd.y;
    tg[14] = bbits + (((u32)m3.z) & ~63u) + c0 + 14; vv[14] = vd.z;
    tg[15] = bbits + (((u32)m3.w) & ~63u) + c0 + 15; vv[15] = vd.w;

    cur[tid] = 0;
    __syncthreads();
#pragma unroll
    for (int j = 0; j < 16; ++j) atomicAdd(&cur[(tg[j] >> RSH) & (NBKT - 1)], 1u);
    __syncthreads();

    // exclusive scan of 512 counters (one per thread)
    {
        const int lane = tid & 63;
        const int wid  = tid >> 6;
        u32 x = cur[tid];
        u32 s = x;
#pragma unroll
        for (int d = 1; d < 64; d <<= 1) {
            u32 n = __shfl_up(s, (unsigned)d, 64);
            if (lane >= d) s += n;
        }
        if (lane == 63) wsum[wid] = s;
        u32 exw = s - x;
        __syncthreads();
        if (tid == 0) {
            u32 run = 0;
#pragma unroll
            for (int w = 0; w < 8; ++w) { u32 t2 = wsum[w]; wsum[w] = run; run += t2; }
        }
        __syncthreads();
        u32 start = wsum[wid] + exw;
        dir[(size_t)sb * NBKT + tid] = (u16)start;
        cur[tid] = start;              // cursor
    }
    __syncthreads();

#pragma unroll
    for (int j = 0; j < 16; ++j) {
        u32 p = atomicAdd(&cur[(tg[j] >> RSH) & (NBKT - 1)], 1u);
        sRec[p] = ((u64)(tg[j] & (RSLOTS - 1)) << 32) | (u64)__float_as_uint(vv[j]);
    }
    __syncthreads();
#pragma unroll
    for (int k = 0; k < 16; ++k) {
        int i = tid + k * 512;
        recA[(size_t)sb * SBS + i] = sRec[i];    // contiguous u64 flush
    }
}

// ============================ directory transpose ============================
// dir[bb*1024+sb][512 lb] -> dirT[bb*512+lb][1024 sb]; 64x64 u16 tiles.
__global__ __launch_bounds__(256) void tposeD(const u16* __restrict__ dir,
                                              u16* __restrict__ dirT)
{
    __shared__ u16 t[64][65];
    const int tx = threadIdx.x;        // 0..63
    const int ty = threadIdx.y;        // 0..3
    const int bb = blockIdx.z;
    const int sb0 = blockIdx.x * 64;   // 16 tiles
    const int lb0 = blockIdx.y * 64;   // 8 tiles
#pragma unroll
    for (int k = 0; k < 16; ++k) {
        int row = k * 4 + ty;          // sb within tile
        t[row][tx] = dir[((size_t)(bb * SB_PER_B + sb0 + row)) * NBKT + lb0 + tx];
    }
    __syncthreads();
#pragma unroll
    for (int k = 0; k < 16; ++k) {
        int row = k * 4 + ty;          // lb within tile
        dirT[((size_t)(bb * NBKT + lb0 + row)) * SB_PER_B + sb0 + tx] = t[tx][row];
    }
}

// ============================ passC ============================
__global__ __launch_bounds__(1024) void passC(const u64* __restrict__ recA,
                                              const u16* __restrict__ dirT,
                                              float* __restrict__ out)
{
    __shared__ float acc[RSLOTS];      // 128 KiB
    __shared__ u32 cSrc[SB_PER_B];     // 4 KiB
    __shared__ u16 cLen[SB_PER_B];     // 2 KiB
    const int tid = threadIdx.x;
    const int bid = blockIdx.x;
    const int w   = ((bid & 7) << 9) | (bid >> 3);   // XCD-chunked bijective swizzle
    const int bb  = w >> 9;
    const int lb  = w & (NBKT - 1);

    {   // chunk table: two contiguous directory rows
        u32 st = dirT[(size_t)w * SB_PER_B + tid];
        u32 en = (lb == NBKT - 1) ? (u32)SBS : (u32)dirT[(size_t)(w + 1) * SB_PER_B + tid];
        cSrc[tid] = (u32)(bb * SB_PER_B + tid) * (u32)SBS + st;
        cLen[tid] = (u16)(en - st);
    }
    for (int i = tid; i < RSLOTS; i += 1024) acc[i] = 0.f;
    __syncthreads();

    // 64 groups of 16 lanes; each iteration a group handles TWO chunks with
    // TWO predicated independent loads each (covers len<=32; Poisson(16) =>
    // P(len>32) ~ 1e-4 handled by rare tail loops). 4-deep MLP per group.
    const int g  = tid >> 4;
    const int gl = tid & 15;
    for (int s2 = g; s2 < SB_PER_B; s2 += 128) {
        const int s3 = s2 + 64;
        u32 srcA = cSrc[s2];  int lenA = (int)cLen[s2];
        u32 srcB = cSrc[s3];  int lenB = (int)cLen[s3];
        u64 a0 = 0, a1 = 0, b0 = 0, b1 = 0;
        const bool pa0 = gl < lenA, pa1 = gl + 16 < lenA;
        const bool pb0 = gl < lenB, pb1 = gl + 16 < lenB;
        if (pa0) a0 = recA[srcA + gl];
        if (pa1) a1 = recA[srcA + gl + 16];
        if (pb0) b0 = recA[srcB + gl];
        if (pb1) b1 = recA[srcB + gl + 16];
        if (pa0) atomicAdd(&acc[(u32)(a0 >> 32)], __uint_as_float((u32)a0));
        if (pa1) atomicAdd(&acc[(u32)(a1 >> 32)], __uint_as_float((u32)a1));
        if (pb0) atomicAdd(&acc[(u32)(b0 >> 32)], __uint_as_float((u32)b0));
        if (pb1) atomicAdd(&acc[(u32)(b1 >> 32)], __uint_as_float((u32)b1));
        for (int off = gl + 32; off < lenA; off += 16) {       // rare tail
            u64 rec = recA[srcA + off];
            atomicAdd(&acc[(u32)(rec >> 32)], __uint_as_float((u32)rec));
        }
        for (int off = gl + 32; off < lenB; off += 16) {       // rare tail
            u64 rec = recA[srcB + off];
            atomicAdd(&acc[(u32)(rec >> 32)], __uint_as_float((u32)rec));
        }
    }
    __syncthreads();

    // nontemporal store: output is written once, never re-read this launch;
    // keeps record lines resident in L2/L3 for other blocks' gathers.
    fv4* o4 = (fv4*)out + ((size_t)w << (RSH - 2));
    const fv4* a4 = (const fv4*)acc;
#pragma unroll
    for (int i = tid; i < RSLOTS / 4; i += 1024)
        __builtin_nontemporal_store(a4[i], o4 + i);
}

// ===================== fallback: direct atomic scatter =====================
__global__ __launch_bounds__(256) void unmaxpool_scatter(
    const float* __restrict__ in, const int* __restrict__ mask,
    float* __restrict__ out)
{
    const long long n4 = N_IN / 4;
    long long gidx = (long long)blockIdx.x * blockDim.x + threadIdx.x;
    const long long stride = (long long)gridDim.x * blockDim.x;
    for (; gidx < n4; gidx += stride) {
        float4 v = reinterpret_cast<const float4*>(in)[gidx];
        int4 m = reinterpret_cast<const int4*>(mask)[gidx];
        long long i0 = gidx * 4;
        u32 ob = ((u32)(i0 >> 23)) << 24;
        u32 c0 = (u32)(i0 & 63);
        atomicAdd(&out[ob + (u32)(m.x & ~63) + c0 + 0], v.x);
        atomicAdd(&out[ob + (u32)(m.y & ~63) + c0 + 1], v.y);
        atomicAdd(&out[ob + (u32)(m.z & ~63) + c0 + 2], v.z);
        atomicAdd(&out[ob + (u32)(m.w & ~63) + c0 + 3], v.w);
    }
}

extern "C" void kernel_launch(void* const* d_in, const int* in_sizes, int n_in,
                              void* d_out, int out_size, void* d_ws, size_t ws_size,
                              hipStream_t stream) {
    const float* in = (const float*)d_in[0];
    const int* mask = (const int*)d_in[1];
    float* out = (float*)d_out;
    char* ws = (char*)d_ws;

    if (d_ws != nullptr && ws_size >= WS_FUSED) {
        u64* recA = (u64*)(ws + OFF_RECA);
        u16* dir  = (u16*)(ws + OFF_DIR);
        u16* dirT = (u16*)(ws + OFF_DIRT);
        passA<<<NSB, 512, 0, stream>>>(in, mask, recA, dir);
        tposeD<<<dim3(16, 8, 8), dim3(64, 4), 0, stream>>>(dir, dirT);
        passC<<<NWIN, 1024, 0, stream>>>(recA, dirT, out);
    } else {
        (void)hipMemsetAsync(out, 0, (size_t)out_size * sizeof(float), stream);
        unmaxpool_scatter<<<2048, 256, 0, stream>>>(in, mask, out);
    }
}

// Round 8
// 620.117 us; speedup vs baseline: 3.0112x; 1.0860x over previous
//
#include <hip/hip_runtime.h>

// UnMaxPoolWithArgmax, two-pass counting-sort at window granularity:
//   passA: per 8192-elem sub-batch (one image batch b each), LDS-sort records
//          by 1024 in-batch window buckets ((tg>>14)&1023); flush contiguous
//          u64 records (rel14<<32 | valbits) + u16 offset directory (amp ~1).
//   tposeD: transpose directory to window-major (2x16 MB, trivial).
//   passC: one block per 2^14-slot window (8192 blocks, 64KB acc -> 2
//          blocks/CU, 100% occupancy); single sweep, 4-deep MLP gather
//          (4 predicated chunk loads per 16-lane group), LDS atomicAdd once
//          per record, nontemporal 64 KB store. Covers whole output.
// target tg = (b<<24) | (mask & ~63) | c0 (27 bits); window = tg>>14 (8192).

typedef unsigned int u32;
typedef unsigned short u16;
typedef unsigned long long u64;

// clang ext-vector types (valid for __builtin_nontemporal_load/store)
typedef int   iv4 __attribute__((ext_vector_type(4)));
typedef float fv4 __attribute__((ext_vector_type(4)));

constexpr long long N_IN = 1LL << 26;      // 67,108,864 elements
constexpr int SBS   = 8192;                // elements per sub-batch
constexpr int NSB   = (int)(N_IN / SBS);   // 8192 sub-batches
constexpr int NBKT  = 1024;                // in-batch window buckets
constexpr int NWIN  = 8192;                // global windows (8 batches * 1024)
constexpr int RSH   = 14;                  // window = 2^14 slots (64 KiB)
constexpr int RSLOTS = 1 << RSH;
constexpr int SB_PER_B = 1024;             // sub-batches per image batch

// ---------------- workspace ----------------
constexpr size_t OFF_RECA = 0;                                   // u64[2^26] = 512 MiB
constexpr size_t OFF_DIR  = (size_t)N_IN * 8;                    // u16[NSB*NBKT] = 16 MiB
constexpr size_t OFF_DIRT = OFF_DIR + (size_t)NSB * NBKT * 2;    // u16[NWIN*SB_PER_B] = 16 MiB
constexpr size_t WS_FUSED = OFF_DIRT + (size_t)NWIN * SB_PER_B * 2;  // ~544 MiB

// ============================ passA ============================
__global__ __launch_bounds__(512) void passA(const float* __restrict__ in,
                                             const int* __restrict__ mask,
                                             u64* __restrict__ recA,
                                             u16* __restrict__ dir)
{
    __shared__ u32 cur[NBKT];      // hist -> starts -> cursors (4 KiB)
    __shared__ u32 wsum[8];
    __shared__ u64 sRec[SBS];      // 64 KiB
    const int tid = threadIdx.x;
    const int sb  = blockIdx.x;
    const int e0  = sb * SBS + tid * 16;

    const iv4* m4 = (const iv4*)mask + (e0 >> 2);
    const fv4* v4 = (const fv4*)in + (e0 >> 2);
    iv4 m0 = __builtin_nontemporal_load(m4 + 0);
    iv4 m1 = __builtin_nontemporal_load(m4 + 1);
    iv4 m2 = __builtin_nontemporal_load(m4 + 2);
    iv4 m3 = __builtin_nontemporal_load(m4 + 3);
    fv4 va = __builtin_nontemporal_load(v4 + 0);
    fv4 vb = __builtin_nontemporal_load(v4 + 1);
    fv4 vc = __builtin_nontemporal_load(v4 + 2);
    fv4 vd = __builtin_nontemporal_load(v4 + 3);
    const u32 bbits = ((u32)(e0 >> 23)) << 24;   // batch bits (HWC = 2^23)
    const u32 c0 = (u32)(e0 & 63);

    u32 tg[16]; float vv[16];
    tg[ 0] = bbits + (((u32)m0.x) & ~63u) + c0 +  0; vv[ 0] = va.x;
    tg[ 1] = bbits + (((u32)m0.y) & ~63u) + c0 +  1; vv[ 1] = va.y;
    tg[ 2] = bbits + (((u32)m0.z) & ~63u) + c0 +  2; vv[ 2] = va.z;
    tg[ 3] = bbits + (((u32)m0.w) & ~63u) + c0 +  3; vv[ 3] = va.w;
    tg[ 4] = bbits + (((u32)m1.x) & ~63u) + c0 +  4; vv[ 4] = vb.x;
    tg[ 5] = bbits + (((u32)m1.y) & ~63u) + c0 +  5; vv[ 5] = vb.y;
    tg[ 6] = bbits + (((u32)m1.z) & ~63u) + c0 +  6; vv[ 6] = vb.z;
    tg[ 7] = bbits + (((u32)m1.w) & ~63u) + c0 +  7; vv[ 7] = vb.w;
    tg[ 8] = bbits + (((u32)m2.x) & ~63u) + c0 +  8; vv[ 8] = vc.x;
    tg[ 9] = bbits + (((u32)m2.y) & ~63u) + c0 +  9; vv[ 9] = vc.y;
    tg[10] = bbits + (((u32)m2.z) & ~63u) + c0 + 10; vv[10] = vc.z;
    tg[11] = bbits + (((u32)m2.w) & ~63u) + c0 + 11; vv[11] = vc.w;
    tg[12] = bbits + (((u32)m3.x) & ~63u) + c0 + 12; vv[12] = vd.x;
    tg[13] = bbits + (((u32)m3.y) & ~63u) + c0 + 13; vv[13] = vd.y;
    tg[14] = bbits + (((u32)m3.z) & ~63u) + c0 + 14; vv[14] = vd.z;
    tg[15] = bbits + (((u32)m3.w) & ~63u) + c0 + 15; vv[15] = vd.w;

    cur[2 * tid] = 0;
    cur[2 * tid + 1] = 0;
    __syncthreads();
#pragma unroll
    for (int j = 0; j < 16; ++j) atomicAdd(&cur[(tg[j] >> RSH) & (NBKT - 1)], 1u);
    __syncthreads();

    // exclusive scan of 1024 counters (2 consecutive per thread)
    {
        const int lane = tid & 63;
        const int wid  = tid >> 6;
        u32 a = cur[2 * tid];
        u32 b = cur[2 * tid + 1];
        u32 sum = a + b;
        u32 s = sum;
#pragma unroll
        for (int d = 1; d < 64; d <<= 1) {
            u32 n = __shfl_up(s, (unsigned)d, 64);
            if (lane >= d) s += n;
        }
        if (lane == 63) wsum[wid] = s;
        u32 exw = s - sum;
        __syncthreads();
        if (tid == 0) {
            u32 run = 0;
#pragma unroll
            for (int w = 0; w < 8; ++w) { u32 t2 = wsum[w]; wsum[w] = run; run += t2; }
        }
        __syncthreads();
        u32 start = wsum[wid] + exw;
        dir[(size_t)sb * NBKT + 2 * tid]     = (u16)start;
        dir[(size_t)sb * NBKT + 2 * tid + 1] = (u16)(start + a);
        cur[2 * tid]     = start;          // cursors
        cur[2 * tid + 1] = start + a;
    }
    __syncthreads();

#pragma unroll
    for (int j = 0; j < 16; ++j) {
        u32 p = atomicAdd(&cur[(tg[j] >> RSH) & (NBKT - 1)], 1u);
        sRec[p] = ((u64)(tg[j] & (RSLOTS - 1)) << 32) | (u64)__float_as_uint(vv[j]);
    }
    __syncthreads();
#pragma unroll
    for (int k = 0; k < 16; ++k) {
        int i = tid + k * 512;
        recA[(size_t)sb * SBS + i] = sRec[i];    // contiguous u64 flush
    }
}

// ============================ directory transpose ============================
// dir[bb*1024+sb][1024 lb] -> dirT[bb*1024+lb][1024 sb]; 64x64 u16 tiles.
__global__ __launch_bounds__(256) void tposeD(const u16* __restrict__ dir,
                                              u16* __restrict__ dirT)
{
    __shared__ u16 t[64][65];
    const int tx = threadIdx.x;        // 0..63
    const int ty = threadIdx.y;        // 0..3
    const int bb = blockIdx.z;
    const int sb0 = blockIdx.x * 64;   // 16 tiles
    const int lb0 = blockIdx.y * 64;   // 16 tiles
#pragma unroll
    for (int k = 0; k < 16; ++k) {
        int row = k * 4 + ty;          // sb within tile
        t[row][tx] = dir[((size_t)(bb * SB_PER_B + sb0 + row)) * NBKT + lb0 + tx];
    }
    __syncthreads();
#pragma unroll
    for (int k = 0; k < 16; ++k) {
        int row = k * 4 + ty;          // lb within tile
        dirT[((size_t)(bb * NBKT + lb0 + row)) * SB_PER_B + sb0 + tx] = t[tx][row];
    }
}

// ============================ passC ============================
__global__ __launch_bounds__(1024, 8) void passC(const u64* __restrict__ recA,
                                                 const u16* __restrict__ dirT,
                                                 float* __restrict__ out)
{
    __shared__ float acc[RSLOTS];      // 64 KiB
    __shared__ u32 cSrc[SB_PER_B];     // 4 KiB
    __shared__ u16 cLen[SB_PER_B];     // 2 KiB
    const int tid = threadIdx.x;
    const int bid = blockIdx.x;
    const int w   = ((bid & 7) << 10) | (bid >> 3);  // XCD-chunked bijective swizzle
    const int bb  = w >> 10;
    const int lb  = w & (NBKT - 1);

    {   // chunk table: two contiguous directory rows
        u32 st = dirT[(size_t)w * SB_PER_B + tid];
        u32 en = (lb == NBKT - 1) ? (u32)SBS : (u32)dirT[(size_t)(w + 1) * SB_PER_B + tid];
        cSrc[tid] = (u32)(bb * SB_PER_B + tid) * (u32)SBS + st;
        cLen[tid] = (u16)(en - st);
    }
    for (int i = tid; i < RSLOTS; i += 1024) acc[i] = 0.f;
    __syncthreads();

    // 64 groups of 16 lanes; each iteration a group handles FOUR chunks with
    // one predicated 16-lane load each (covers len<=16; Poisson(8) =>
    // P(len>16) ~ 0.2%, handled by rare tail loops). 4-deep MLP per group.
    const int g  = tid >> 4;
    const int gl = tid & 15;
    for (int s0 = g; s0 < SB_PER_B; s0 += 256) {
        const int s1 = s0 + 64, s2 = s0 + 128, s3 = s0 + 192;
        u32 srcA = cSrc[s0];  int lenA = (int)cLen[s0];
        u32 srcB = cSrc[s1];  int lenB = (int)cLen[s1];
        u32 srcC = cSrc[s2];  int lenC = (int)cLen[s2];
        u32 srcD = cSrc[s3];  int lenD = (int)cLen[s3];
        u64 a0 = 0, b0 = 0, c0 = 0, d0 = 0;
        const bool pa = gl < lenA;
        const bool pb = gl < lenB;
        const bool pc = gl < lenC;
        const bool pd = gl < lenD;
        if (pa) a0 = recA[srcA + gl];
        if (pb) b0 = recA[srcB + gl];
        if (pc) c0 = recA[srcC + gl];
        if (pd) d0 = recA[srcD + gl];
        if (pa) atomicAdd(&acc[(u32)(a0 >> 32)], __uint_as_float((u32)a0));
        if (pb) atomicAdd(&acc[(u32)(b0 >> 32)], __uint_as_float((u32)b0));
        if (pc) atomicAdd(&acc[(u32)(c0 >> 32)], __uint_as_float((u32)c0));
        if (pd) atomicAdd(&acc[(u32)(d0 >> 32)], __uint_as_float((u32)d0));
        for (int off = gl + 16; off < lenA; off += 16) {        // rare tails
            u64 rec = recA[srcA + off];
            atomicAdd(&acc[(u32)(rec >> 32)], __uint_as_float((u32)rec));
        }
        for (int off = gl + 16; off < lenB; off += 16) {
            u64 rec = recA[srcB + off];
            atomicAdd(&acc[(u32)(rec >> 32)], __uint_as_float((u32)rec));
        }
        for (int off = gl + 16; off < lenC; off += 16) {
            u64 rec = recA[srcC + off];
            atomicAdd(&acc[(u32)(rec >> 32)], __uint_as_float((u32)rec));
        }
        for (int off = gl + 16; off < lenD; off += 16) {
            u64 rec = recA[srcD + off];
            atomicAdd(&acc[(u32)(rec >> 32)], __uint_as_float((u32)rec));
        }
    }
    __syncthreads();

    // nontemporal store: output is written once, never re-read this launch;
    // keeps record lines resident in L2/L3 for other blocks' gathers.
    fv4* o4 = (fv4*)out + ((size_t)w << (RSH - 2));
    const fv4* a4 = (const fv4*)acc;
#pragma unroll
    for (int i = tid; i < RSLOTS / 4; i += 1024)
        __builtin_nontemporal_store(a4[i], o4 + i);
}

// ===================== fallback: direct atomic scatter =====================
__global__ __launch_bounds__(256) void unmaxpool_scatter(
    const float* __restrict__ in, const int* __restrict__ mask,
    float* __restrict__ out)
{
    const long long n4 = N_IN / 4;
    long long gidx = (long long)blockIdx.x * blockDim.x + threadIdx.x;
    const long long stride = (long long)gridDim.x * blockDim.x;
    for (; gidx < n4; gidx += stride) {
        float4 v = reinterpret_cast<const float4*>(in)[gidx];
        int4 m = reinterpret_cast<const int4*>(mask)[gidx];
        long long i0 = gidx * 4;
        u32 ob = ((u32)(i0 >> 23)) << 24;
        u32 c0 = (u32)(i0 & 63);
        atomicAdd(&out[ob + (u32)(m.x & ~63) + c0 + 0], v.x);
        atomicAdd(&out[ob + (u32)(m.y & ~63) + c0 + 1], v.y);
        atomicAdd(&out[ob + (u32)(m.z & ~63) + c0 + 2], v.z);
        atomicAdd(&out[ob + (u32)(m.w & ~63) + c0 + 3], v.w);
    }
}

extern "C" void kernel_launch(void* const* d_in, const int* in_sizes, int n_in,
                              void* d_out, int out_size, void* d_ws, size_t ws_size,
                              hipStream_t stream) {
    const float* in = (const float*)d_in[0];
    const int* mask = (const int*)d_in[1];
    float* out = (float*)d_out;
    char* ws = (char*)d_ws;

    if (d_ws != nullptr && ws_size >= WS_FUSED) {
        u64* recA = (u64*)(ws + OFF_RECA);
        u16* dir  = (u16*)(ws + OFF_DIR);
        u16* dirT = (u16*)(ws + OFF_DIRT);
        passA<<<NSB, 512, 0, stream>>>(in, mask, recA, dir);
        tposeD<<<dim3(16, 16, 8), dim3(64, 4), 0, stream>>>(dir, dirT);
        passC<<<NWIN, 1024, 0, stream>>>(recA, dirT, out);
    } else {
        (void)hipMemsetAsync(out, 0, (size_t)out_size * sizeof(float), stream);
        unmaxpool_scatter<<<2048, 256, 0, stream>>>(in, mask, out);
    }
}